// Round 1
// baseline (268.098 us; speedup 1.0000x reference)
//
#include <hip/hip_runtime.h>
#include <cstdint>

#define NHEAD 16
#define DHEAD 64
#define SEQ   2048
#define DMODEL 1024
#define MTOT  4096
#define NQKV  3072

typedef __bf16 bf16x8 __attribute__((ext_vector_type(8)));
typedef short  s16x4  __attribute__((ext_vector_type(4)));
typedef float  f32x4  __attribute__((ext_vector_type(4)));

__device__ __forceinline__ unsigned short f2bf(float f) {
  union { float f; unsigned u; } v; v.f = f;
  unsigned r = v.u + 0x7fffu + ((v.u >> 16) & 1u);
  return (unsigned short)(r >> 16);
}

// async global->LDS, 16B per lane. LDS dest must be wave-uniform base + lane*16.
__device__ __forceinline__ void gl_lds16(const void* g, void* l) {
  __builtin_amdgcn_global_load_lds(
      reinterpret_cast<const __attribute__((address_space(1))) unsigned int*>(
          reinterpret_cast<uintptr_t>(g)),
      reinterpret_cast<__attribute__((address_space(3))) unsigned int*>(
          reinterpret_cast<uintptr_t>(l)),
      16, 0, 0);
}

#if __has_builtin(__builtin_amdgcn_mfma_f32_16x16x16bf16_1k)
#define MFMA_PV(a, b, c) __builtin_amdgcn_mfma_f32_16x16x16bf16_1k(a, b, c, 0, 0, 0)
#else
__device__ __forceinline__ f32x4 mfma_pv_asm(s16x4 a, s16x4 b, f32x4 c) {
  f32x4 d;
  asm volatile("v_mfma_f32_16x16x16_bf16 %0, %1, %2, %3"
               : "=v"(d) : "v"(a), "v"(b), "v"(c));
  return d;
}
#define MFMA_PV(a, b, c) mfma_pv_asm(a, b, c)
#endif

// ---------------- fp32 -> bf16 elementwise (input) ----------------
__global__ void k_cvt_bf16(const float* __restrict__ x,
                           unsigned short* __restrict__ y, int n4) {
  int i = blockIdx.x * blockDim.x + threadIdx.x;
  if (i >= n4) return;
  float4 v = reinterpret_cast<const float4*>(x)[i];
  ushort4 o;
  o.x = f2bf(v.x); o.y = f2bf(v.y); o.z = f2bf(v.z); o.w = f2bf(v.w);
  reinterpret_cast<ushort4*>(y)[i] = o;
}

// ---------------- fp32 W[K][N] -> bf16 W^T[N][K] ----------------
__global__ void k_transpose_cvt(const float* __restrict__ W,
                                unsigned short* __restrict__ WT, int K, int N) {
  __shared__ unsigned short t[32][33];
  int n0 = blockIdx.x * 32, k0 = blockIdx.y * 32;
  int tx = threadIdx.x, ty = threadIdx.y;
  for (int i = ty; i < 32; i += 8)
    t[i][tx] = f2bf(W[(size_t)(k0 + i) * N + n0 + tx]);
  __syncthreads();
  for (int i = ty; i < 32; i += 8)
    WT[(size_t)(n0 + i) * K + k0 + tx] = t[tx][i];
}

// ---------------- GEMM1: qkv = A[4096x1024] * WqkvT[3072x1024]^T + b ----------------
// epilogue: q -> qbf [B,H,L,64]; k -> d_out(fp32) + kbf [B,H,L,64];
//           v -> d_out(fp32) + vtbf [B,H,64,L] (pre-transposed for attention PV)
__global__ __launch_bounds__(256) void k_gemm_qkv(
    const unsigned short* __restrict__ A, const unsigned short* __restrict__ Bt,
    const float* __restrict__ bias, float* __restrict__ outbase,
    unsigned short* __restrict__ qbf, unsigned short* __restrict__ kbf,
    unsigned short* __restrict__ vtbf) {
  __shared__ __attribute__((aligned(16))) unsigned short As[128 * 32];
  __shared__ __attribute__((aligned(16))) unsigned short Bs[128 * 32];
  const int tid = threadIdx.x, lane = tid & 63;
  const int w = tid >> 6, wm = w >> 1, wn = w & 1;
  const int c = lane & 15, q = lane >> 4;
  const int bm = blockIdx.x * 128, bn = blockIdx.y * 128;
  const int srow = tid >> 2, scol = (tid & 3) * 8;
  const unsigned short* Ag = A + (size_t)(bm + srow) * DMODEL + scol;
  const unsigned short* Bg = Bt + (size_t)(bn + srow) * DMODEL + scol;
  f32x4 acc[4][4] = {};

  for (int kt = 0; kt < DMODEL / 32; ++kt) {
    if (kt) __syncthreads();
    const int k0 = kt * 32;
    gl_lds16(Ag + k0, As + tid * 8);
    gl_lds16(Ag + (size_t)64 * DMODEL + k0, As + 2048 + tid * 8);
    gl_lds16(Bg + k0, Bs + tid * 8);
    gl_lds16(Bg + (size_t)64 * DMODEL + k0, Bs + 2048 + tid * 8);
    __syncthreads();
    bf16x8 af[4], bfr[4];
#pragma unroll
    for (int i = 0; i < 4; ++i)
      af[i] = *reinterpret_cast<const bf16x8*>(As + (wm * 64 + i * 16 + c) * 32 + q * 8);
#pragma unroll
    for (int j = 0; j < 4; ++j)
      bfr[j] = *reinterpret_cast<const bf16x8*>(Bs + (wn * 64 + j * 16 + c) * 32 + q * 8);
#pragma unroll
    for (int i = 0; i < 4; ++i)
#pragma unroll
      for (int j = 0; j < 4; ++j)
        acc[i][j] = __builtin_amdgcn_mfma_f32_16x16x32_bf16(af[i], bfr[j], acc[i][j], 0, 0, 0);
  }

  const int sec = bn >> 10;  // 0=q 1=k 2=v (block-uniform)
#pragma unroll
  for (int j = 0; j < 4; ++j) {
    const int gn = bn + wn * 64 + j * 16 + c;
    const float bv = bias[gn];
    const int cc = gn & 1023, hh = cc >> 6, dd = cc & 63;
#pragma unroll
    for (int i = 0; i < 4; ++i) {
#pragma unroll
      for (int r = 0; r < 4; ++r) {
        const int gm = bm + wm * 64 + i * 16 + q * 4 + r;
        const int bb = gm >> 11, tok = gm & 2047;
        const float val = acc[i][j][r] + bv;
        const size_t hoff = ((size_t)(bb * NHEAD + hh) * SEQ + tok) * DHEAD + dd;
        if (sec == 0) {
          qbf[hoff] = f2bf(val);
        } else if (sec == 1) {
          outbase[(size_t)4194304 + (size_t)gm * DMODEL + cc] = val;
          kbf[hoff] = f2bf(val);
        } else {
          outbase[(size_t)8388608 + (size_t)gm * DMODEL + cc] = val;
          vtbf[((size_t)(bb * NHEAD + hh) * DHEAD + dd) * SEQ + tok] = f2bf(val);
        }
      }
    }
  }
}

// ---------------- flash attention (causal), S^T trick ----------------
// computes S^T = K*Q^T so softmax state is per-lane (q = lane&15) and
// P^T C-layout registers are directly the B-frag of O^T = V^T * P^T.
__global__ __launch_bounds__(256) void k_attn(
    const unsigned short* __restrict__ qbf, const unsigned short* __restrict__ kbf,
    const unsigned short* __restrict__ vtbf, unsigned short* __restrict__ aout) {
  __shared__ __attribute__((aligned(16))) unsigned short Qs[128 * 64];
  __shared__ __attribute__((aligned(16))) unsigned short Ks[128 * 64];
  __shared__ __attribute__((aligned(16))) unsigned short Vs[64 * 136];  // +8 pad

  const int tid = threadIdx.x, lane = tid & 63, w = tid >> 6;
  const int c = lane & 15, q = lane >> 4;
  const int bh = blockIdx.x;                 // 0..31
  const int qt = 15 - (int)blockIdx.y;       // heavy q-tiles dispatched first
  const int b = bh >> 4, h = bh & 15;
  const size_t hoff = (size_t)bh * SEQ * DHEAD;

  {  // stage Q tile [128][64] once
    const unsigned short* qg = qbf + hoff + (size_t)qt * 128 * DHEAD;
    const int row = tid >> 3, ch = (tid & 7) * 8;
#pragma unroll
    for (int is = 0; is < 4; ++is)
      gl_lds16(qg + (size_t)(row + is * 32) * DHEAD + ch, Qs + is * 2048 + tid * 8);
  }
  __syncthreads();

  bf16x8 qb[2][2];  // B-frags of Q^T, held across the whole k-loop
#pragma unroll
  for (int nj = 0; nj < 2; ++nj)
#pragma unroll
    for (int kf = 0; kf < 2; ++kf)
      qb[nj][kf] = *reinterpret_cast<const bf16x8*>(
          Qs + (w * 32 + nj * 16 + c) * 64 + kf * 32 + q * 8);

  f32x4 o[4][2] = {};                       // O^T accum: d=(q*4+r)+dm*16, q-col=c
  float mrun[2] = {-__builtin_inff(), -__builtin_inff()};
  float lrun[2] = {0.f, 0.f};
  const float sscale = 0.125f * 1.44269504088896340736f;  // 1/sqrt(64) * log2(e)

  const int krow = tid >> 3, kch = (tid & 7) * 8;
  const int vrow = tid >> 4, vch = (tid & 15) * 8;
  const unsigned short* kgb = kbf + hoff;
  const unsigned short* vgb = vtbf + (size_t)bh * DHEAD * SEQ;

  for (int kt = 0; kt <= qt; ++kt) {
    __syncthreads();  // prev iter compute done before overwriting Ks/Vs
    const unsigned short* kg = kgb + (size_t)kt * 128 * DHEAD;
#pragma unroll
    for (int is = 0; is < 4; ++is)
      gl_lds16(kg + (size_t)(krow + is * 32) * DHEAD + kch, Ks + is * 2048 + tid * 8);
    const unsigned short* vg = vgb + kt * 128;
    uint4 vv[4];
#pragma unroll
    for (int is = 0; is < 4; ++is)
      vv[is] = *reinterpret_cast<const uint4*>(vg + (size_t)(vrow + is * 16) * SEQ + vch);
#pragma unroll
    for (int is = 0; is < 4; ++is)
      *reinterpret_cast<uint4*>(Vs + (vrow + is * 16) * 136 + vch) = vv[is];
    __syncthreads();

    // S^T[k][q] = sum_d K[k][d] Q[q][d]
    f32x4 s[8][2];
#pragma unroll
    for (int mi = 0; mi < 8; ++mi) {
      const bf16x8 ak0 = *reinterpret_cast<const bf16x8*>(Ks + (mi * 16 + c) * 64 + q * 8);
      const bf16x8 ak1 = *reinterpret_cast<const bf16x8*>(Ks + (mi * 16 + c) * 64 + 32 + q * 8);
#pragma unroll
      for (int nj = 0; nj < 2; ++nj) {
        f32x4 t = {};
        t = __builtin_amdgcn_mfma_f32_16x16x32_bf16(ak0, qb[nj][0], t, 0, 0, 0);
        t = __builtin_amdgcn_mfma_f32_16x16x32_bf16(ak1, qb[nj][1], t, 0, 0, 0);
        s[mi][nj] = t;
      }
    }

    const bool diag = (kt == qt);
    s16x4 pb[2][8];
#pragma unroll
    for (int nj = 0; nj < 2; ++nj) {
      const int qloc = w * 32 + nj * 16 + c;  // local q row in the 128-tile
      float mx = -__builtin_inff();
#pragma unroll
      for (int mi = 0; mi < 8; ++mi)
#pragma unroll
        for (int r = 0; r < 4; ++r) {
          float v = s[mi][nj][r] * sscale;
          if (diag && (mi * 16 + q * 4 + r > qloc)) v = -__builtin_inff();
          s[mi][nj][r] = v;
          mx = fmaxf(mx, v);
        }
      mx = fmaxf(mx, __shfl_xor(mx, 16));
      mx = fmaxf(mx, __shfl_xor(mx, 32));
      const float mn = fmaxf(mrun[nj], mx);
      const float al = exp2f(mrun[nj] - mn);
      mrun[nj] = mn;
      float rs = 0.f;
#pragma unroll
      for (int mi = 0; mi < 8; ++mi) {
        float p0 = exp2f(s[mi][nj][0] - mn);
        float p1 = exp2f(s[mi][nj][1] - mn);
        float p2 = exp2f(s[mi][nj][2] - mn);
        float p3 = exp2f(s[mi][nj][3] - mn);
        rs += (p0 + p1) + (p2 + p3);
        s16x4 pv;
        pv[0] = (short)f2bf(p0); pv[1] = (short)f2bf(p1);
        pv[2] = (short)f2bf(p2); pv[3] = (short)f2bf(p3);
        pb[nj][mi] = pv;
      }
      rs += __shfl_xor(rs, 16);
      rs += __shfl_xor(rs, 32);
      lrun[nj] = lrun[nj] * al + rs;
#pragma unroll
      for (int dm = 0; dm < 4; ++dm) o[dm][nj] *= al;
    }

    // O^T += V^T * P^T   (A-frag: V^T rows contiguous; B-frag = pb directly)
#pragma unroll
    for (int dm = 0; dm < 4; ++dm)
#pragma unroll
      for (int kf = 0; kf < 8; ++kf) {
        const s16x4 av = *reinterpret_cast<const s16x4*>(
            Vs + (dm * 16 + c) * 136 + kf * 16 + q * 4);
#pragma unroll
        for (int nj = 0; nj < 2; ++nj)
          o[dm][nj] = MFMA_PV(av, pb[nj][kf], o[dm][nj]);
      }
  }

  // epilogue: O[token][h*64+d], 4 consecutive d per lane -> 8B stores
  const int rowb = b * SEQ + qt * 128 + w * 32;
#pragma unroll
  for (int nj = 0; nj < 2; ++nj) {
    const float linv = 1.0f / lrun[nj];
    const int row = rowb + nj * 16 + c;
#pragma unroll
    for (int dm = 0; dm < 4; ++dm) {
      ushort4 ov;
      ov.x = f2bf(o[dm][nj][0] * linv);
      ov.y = f2bf(o[dm][nj][1] * linv);
      ov.z = f2bf(o[dm][nj][2] * linv);
      ov.w = f2bf(o[dm][nj][3] * linv);
      *reinterpret_cast<ushort4*>(aout + (size_t)row * DMODEL + h * 64 + dm * 16 + q * 4) = ov;
    }
  }
}

// ---------------- GEMM2: out = Aout[4096x1024] * WoutT[1024x1024]^T + b ----------------
__global__ __launch_bounds__(256) void k_gemm_out(
    const unsigned short* __restrict__ A, const unsigned short* __restrict__ Bt,
    const float* __restrict__ bias, float* __restrict__ C) {
  __shared__ __attribute__((aligned(16))) unsigned short As[128 * 32];
  __shared__ __attribute__((aligned(16))) unsigned short Bs[128 * 32];
  const int tid = threadIdx.x, lane = tid & 63;
  const int w = tid >> 6, wm = w >> 1, wn = w & 1;
  const int c = lane & 15, q = lane >> 4;
  const int bm = blockIdx.x * 128, bn = blockIdx.y * 128;
  const int srow = tid >> 2, scol = (tid & 3) * 8;
  const unsigned short* Ag = A + (size_t)(bm + srow) * DMODEL + scol;
  const unsigned short* Bg = Bt + (size_t)(bn + srow) * DMODEL + scol;
  f32x4 acc[4][4] = {};

  for (int kt = 0; kt < DMODEL / 32; ++kt) {
    if (kt) __syncthreads();
    const int k0 = kt * 32;
    gl_lds16(Ag + k0, As + tid * 8);
    gl_lds16(Ag + (size_t)64 * DMODEL + k0, As + 2048 + tid * 8);
    gl_lds16(Bg + k0, Bs + tid * 8);
    gl_lds16(Bg + (size_t)64 * DMODEL + k0, Bs + 2048 + tid * 8);
    __syncthreads();
    bf16x8 af[4], bfr[4];
#pragma unroll
    for (int i = 0; i < 4; ++i)
      af[i] = *reinterpret_cast<const bf16x8*>(As + (wm * 64 + i * 16 + c) * 32 + q * 8);
#pragma unroll
    for (int j = 0; j < 4; ++j)
      bfr[j] = *reinterpret_cast<const bf16x8*>(Bs + (wn * 64 + j * 16 + c) * 32 + q * 8);
#pragma unroll
    for (int i = 0; i < 4; ++i)
#pragma unroll
      for (int j = 0; j < 4; ++j)
        acc[i][j] = __builtin_amdgcn_mfma_f32_16x16x32_bf16(af[i], bfr[j], acc[i][j], 0, 0, 0);
  }

#pragma unroll
  for (int j = 0; j < 4; ++j) {
    const int gn = bn + wn * 64 + j * 16 + c;
    const float bv = bias[gn];
#pragma unroll
    for (int i = 0; i < 4; ++i)
#pragma unroll
      for (int r = 0; r < 4; ++r) {
        const int gm = bm + wm * 64 + i * 16 + q * 4 + r;
        C[(size_t)gm * DMODEL + gn] = acc[i][j][r] + bv;
      }
  }
}

extern "C" void kernel_launch(void* const* d_in, const int* in_sizes, int n_in,
                              void* d_out, int out_size, void* d_ws, size_t ws_size,
                              hipStream_t stream) {
  (void)in_sizes; (void)n_in; (void)out_size; (void)ws_size;
  const float* input = (const float*)d_in[0];
  // d_in[1] = causal mask, implemented analytically
  const float* W_qkv = (const float*)d_in[2];
  const float* b_qkv = (const float*)d_in[3];
  const float* W_out = (const float*)d_in[4];
  const float* b_out = (const float*)d_in[5];
  float* out = (float*)d_out;

  unsigned char* ws = (unsigned char*)d_ws;
  unsigned short* Abf   = (unsigned short*)(ws + 0);          // 8 MB  [4096][1024]
  unsigned short* WqkvT = (unsigned short*)(ws + 8388608);    // 6 MB  [3072][1024]
  unsigned short* WoutT = (unsigned short*)(ws + 14680064);   // 2 MB  [1024][1024]
  unsigned short* Qbf   = (unsigned short*)(ws + 16777216);   // 8 MB  [B,H,L,64]
  unsigned short* Kbf   = (unsigned short*)(ws + 25165824);   // 8 MB  [B,H,L,64]
  unsigned short* VTbf  = (unsigned short*)(ws + 33554432);   // 8 MB  [B,H,64,L]
  unsigned short* Aout  = (unsigned short*)(ws + 41943040);   // 8 MB  [4096][1024]

  k_cvt_bf16<<<4096, 256, 0, stream>>>(input, Abf, 1048576);
  k_transpose_cvt<<<dim3(96, 32), dim3(32, 8), 0, stream>>>(W_qkv, WqkvT, 1024, 3072);
  k_transpose_cvt<<<dim3(32, 32), dim3(32, 8), 0, stream>>>(W_out, WoutT, 1024, 1024);
  k_gemm_qkv<<<dim3(32, 24), 256, 0, stream>>>(Abf, WqkvT, b_qkv, out, Qbf, Kbf, VTbf);
  k_attn<<<dim3(32, 16), 256, 0, stream>>>(Qbf, Kbf, VTbf, Aout);
  k_gemm_out<<<dim3(32, 8), 256, 0, stream>>>(Aout, WoutT, b_out, out);
}

// Round 2
// 229.599 us; speedup vs baseline: 1.1677x; 1.1677x over previous
//
#include <hip/hip_runtime.h>
#include <cstdint>

#define NHEAD 16
#define DHEAD 64
#define SEQ   2048
#define DMODEL 1024
#define MTOT  4096
#define NQKV  3072

typedef __bf16 bf16x8 __attribute__((ext_vector_type(8)));
typedef short  s16x4  __attribute__((ext_vector_type(4)));
typedef float  f32x4  __attribute__((ext_vector_type(4)));

__device__ __forceinline__ unsigned short f2bf(float f) {
  union { float f; unsigned u; } v; v.f = f;
  unsigned r = v.u + 0x7fffu + ((v.u >> 16) & 1u);
  return (unsigned short)(r >> 16);
}

// async global->LDS, 16B per lane. LDS dest must be wave-uniform base + lane*16.
__device__ __forceinline__ void gl_lds16(const void* g, void* l) {
  __builtin_amdgcn_global_load_lds(
      reinterpret_cast<const __attribute__((address_space(1))) unsigned int*>(
          reinterpret_cast<uintptr_t>(g)),
      reinterpret_cast<__attribute__((address_space(3))) unsigned int*>(
          reinterpret_cast<uintptr_t>(l)),
      16, 0, 0);
}

#if __has_builtin(__builtin_amdgcn_mfma_f32_16x16x16bf16_1k)
#define MFMA_PV(a, b, c) __builtin_amdgcn_mfma_f32_16x16x16bf16_1k(a, b, c, 0, 0, 0)
#else
__device__ __forceinline__ f32x4 mfma_pv_asm(s16x4 a, s16x4 b, f32x4 c) {
  f32x4 d;
  asm volatile("v_mfma_f32_16x16x16_bf16 %0, %1, %2, %3"
               : "=v"(d) : "v"(a), "v"(b), "v"(c));
  return d;
}
#define MFMA_PV(a, b, c) mfma_pv_asm(a, b, c)
#endif

// ---------------- fp32 -> bf16 elementwise (input) ----------------
__global__ void k_cvt_bf16(const float* __restrict__ x,
                           unsigned short* __restrict__ y, int n4) {
  int i = blockIdx.x * blockDim.x + threadIdx.x;
  if (i >= n4) return;
  float4 v = reinterpret_cast<const float4*>(x)[i];
  ushort4 o;
  o.x = f2bf(v.x); o.y = f2bf(v.y); o.z = f2bf(v.z); o.w = f2bf(v.w);
  reinterpret_cast<ushort4*>(y)[i] = o;
}

// ---------------- fp32 W[K][N] -> bf16 W^T[N][K] ----------------
__global__ void k_transpose_cvt(const float* __restrict__ W,
                                unsigned short* __restrict__ WT, int K, int N) {
  __shared__ unsigned short t[32][33];
  int n0 = blockIdx.x * 32, k0 = blockIdx.y * 32;
  int tx = threadIdx.x, ty = threadIdx.y;
  for (int i = ty; i < 32; i += 8)
    t[i][tx] = f2bf(W[(size_t)(k0 + i) * N + n0 + tx]);
  __syncthreads();
  for (int i = ty; i < 32; i += 8)
    WT[(size_t)(n0 + i) * K + k0 + tx] = t[tx][i];
}

// ---------------- bf16 V [bh][tok][64] -> V^T [bh][64][tok] ----------------
__global__ void k_vtrans(const unsigned short* __restrict__ v,
                         unsigned short* __restrict__ vt) {
  __shared__ unsigned short t[32][33];
  const int bh = blockIdx.z;
  const int t0 = blockIdx.x * 32, d0 = blockIdx.y * 32;
  const int tx = threadIdx.x, ty = threadIdx.y;
  const unsigned short* vb = v + (size_t)bh * SEQ * DHEAD;
  unsigned short* vtb = vt + (size_t)bh * DHEAD * SEQ;
  for (int i = ty; i < 32; i += 8)
    t[i][tx] = vb[(size_t)(t0 + i) * DHEAD + d0 + tx];
  __syncthreads();
  for (int i = ty; i < 32; i += 8)
    vtb[(size_t)(d0 + i) * SEQ + t0 + tx] = t[tx][i];
}

// ---------------- GEMM1: qkv = A[4096x1024] * WqkvT[3072x1024]^T + b ----------------
__global__ __launch_bounds__(256) void k_gemm_qkv(
    const unsigned short* __restrict__ A, const unsigned short* __restrict__ Bt,
    const float* __restrict__ bias, float* __restrict__ outbase,
    unsigned short* __restrict__ qbf, unsigned short* __restrict__ kbf,
    unsigned short* __restrict__ vbf) {
  __shared__ __attribute__((aligned(16))) unsigned short As[128 * 32];
  __shared__ __attribute__((aligned(16))) unsigned short Bs[128 * 32];
  const int tid = threadIdx.x, lane = tid & 63;
  const int w = tid >> 6, wm = w >> 1, wn = w & 1;
  const int c = lane & 15, q = lane >> 4;
  const int bm = blockIdx.x * 128, bn = blockIdx.y * 128;
  const int srow = tid >> 2, scol = (tid & 3) * 8;
  const unsigned short* Ag = A + (size_t)(bm + srow) * DMODEL + scol;
  const unsigned short* Bg = Bt + (size_t)(bn + srow) * DMODEL + scol;
  f32x4 acc[4][4] = {};

  for (int kt = 0; kt < DMODEL / 32; ++kt) {
    if (kt) __syncthreads();
    const int k0 = kt * 32;
    gl_lds16(Ag + k0, As + tid * 8);
    gl_lds16(Ag + (size_t)64 * DMODEL + k0, As + 2048 + tid * 8);
    gl_lds16(Bg + k0, Bs + tid * 8);
    gl_lds16(Bg + (size_t)64 * DMODEL + k0, Bs + 2048 + tid * 8);
    __syncthreads();
    bf16x8 af[4], bfr[4];
#pragma unroll
    for (int i = 0; i < 4; ++i)
      af[i] = *reinterpret_cast<const bf16x8*>(As + (wm * 64 + i * 16 + c) * 32 + q * 8);
#pragma unroll
    for (int j = 0; j < 4; ++j)
      bfr[j] = *reinterpret_cast<const bf16x8*>(Bs + (wn * 64 + j * 16 + c) * 32 + q * 8);
#pragma unroll
    for (int i = 0; i < 4; ++i)
#pragma unroll
      for (int j = 0; j < 4; ++j)
        acc[i][j] = __builtin_amdgcn_mfma_f32_16x16x32_bf16(af[i], bfr[j], acc[i][j], 0, 0, 0);
  }

  const int sec = bn >> 10;  // 0=q 1=k 2=v (block-uniform)
#pragma unroll
  for (int j = 0; j < 4; ++j) {
    const int gn = bn + wn * 64 + j * 16 + c;
    const float bv = bias[gn];
    const int cc = gn & 1023, hh = cc >> 6, dd = cc & 63;
#pragma unroll
    for (int i = 0; i < 4; ++i) {
#pragma unroll
      for (int r = 0; r < 4; ++r) {
        const int gm = bm + wm * 64 + i * 16 + q * 4 + r;
        const int bb = gm >> 11, tok = gm & 2047;
        const float val = acc[i][j][r] + bv;
        const size_t hoff = ((size_t)(bb * NHEAD + hh) * SEQ + tok) * DHEAD + dd;
        if (sec == 0) {
          qbf[hoff] = f2bf(val);
        } else if (sec == 1) {
          outbase[(size_t)4194304 + (size_t)gm * DMODEL + cc] = val;
          kbf[hoff] = f2bf(val);
        } else {
          outbase[(size_t)8388608 + (size_t)gm * DMODEL + cc] = val;
          vbf[hoff] = f2bf(val);
        }
      }
    }
  }
}

// ---------------- flash attention (causal), S^T trick, 64-row Q tiles ----------------
// S^T = K*Q^T: softmax state per-lane (q-col = lane&15); P^T C-layout regs are
// directly the B-frag of O^T = V^T * P^T. K/V LDS XOR-swizzled (chunk^row&7)
// so frag ds_read_b128/b64 spread over all 32 banks.
__global__ __launch_bounds__(256) void k_attn(
    const unsigned short* __restrict__ qbf, const unsigned short* __restrict__ kbf,
    const unsigned short* __restrict__ vtbf, unsigned short* __restrict__ aout) {
  __shared__ __attribute__((aligned(16))) unsigned short Ks[128 * 64];  // 16 KB swizzled
  __shared__ __attribute__((aligned(16))) unsigned short Vs[64 * 128];  // 16 KB swizzled

  const int tid = threadIdx.x, lane = tid & 63, w = tid >> 6;
  const int c = lane & 15, q = lane >> 4;
  // work-balanced qsub permutation: each CU's 4 resident blocks sum to ~34 k-iters
  const int oo = blockIdx.x >> 5, kk = oo & 7, ssl = oo >> 3;
  const int qsub = (ssl == 0) ? (31 - kk) : (ssl == 1) ? kk
                 : (ssl == 2) ? (23 - kk) : (8 + kk);
  const int bh = blockIdx.x & 31;
  const int kmax = qsub >> 1;
  const size_t hoff = (size_t)bh * SEQ * DHEAD;

  // Q B-frags straight from global (row = qsub*64 + w*16 + c)
  const unsigned short* qg = qbf + hoff + (size_t)(qsub * 64 + w * 16 + c) * DHEAD;
  const bf16x8 qb0 = *reinterpret_cast<const bf16x8*>(qg + q * 8);
  const bf16x8 qb1 = *reinterpret_cast<const bf16x8*>(qg + 32 + q * 8);

  f32x4 o[4] = {};
  float mrun = -__builtin_inff(), lrun = 0.f;
  const float sscale = 0.125f * 1.44269504088896340736f;  // 1/sqrt(64)*log2e
  const int qloc = (qsub & 1) * 64 + w * 16 + c;          // q pos within 128 k-tile
  const int cx = c & 7;                                   // frag-read swizzle key

  const int krow = tid >> 3, kswz = (tid & 7) ^ (krow & 7);
  const int vrow = tid >> 4, vswz = (tid & 15) ^ (vrow & 7);
  const unsigned short* kgb = kbf + hoff;
  const unsigned short* vgb = vtbf + (size_t)bh * DHEAD * SEQ;

  for (int kt = 0; kt <= kmax; ++kt) {
    __syncthreads();
    const unsigned short* kg = kgb + (size_t)kt * 128 * DHEAD;
#pragma unroll
    for (int is = 0; is < 4; ++is)
      gl_lds16(kg + (krow + is * 32) * 64 + kswz * 8, Ks + is * 2048 + tid * 8);
    const unsigned short* vg = vgb + kt * 128;
#pragma unroll
    for (int is = 0; is < 4; ++is)
      gl_lds16(vg + (size_t)(vrow + is * 16) * SEQ + vswz * 8, Vs + is * 2048 + tid * 8);
    __syncthreads();

    // S^T[k][q] = sum_d K[k][d] Q[q][d]
    f32x4 s[8];
#pragma unroll
    for (int mi = 0; mi < 8; ++mi) {
      const unsigned short* kr = Ks + (mi * 16 + c) * 64;
      const bf16x8 ak0 = *reinterpret_cast<const bf16x8*>(kr + (q ^ cx) * 8);
      const bf16x8 ak1 = *reinterpret_cast<const bf16x8*>(kr + ((4 + q) ^ cx) * 8);
      f32x4 t = {};
      t = __builtin_amdgcn_mfma_f32_16x16x32_bf16(ak0, qb0, t, 0, 0, 0);
      t = __builtin_amdgcn_mfma_f32_16x16x32_bf16(ak1, qb1, t, 0, 0, 0);
      s[mi] = t;
    }

    if (kt == kmax) {  // block-uniform diag branch
#pragma unroll
      for (int mi = 0; mi < 8; ++mi)
#pragma unroll
        for (int r = 0; r < 4; ++r)
          if (mi * 16 + q * 4 + r > qloc) s[mi][r] = -__builtin_inff();
    }

    float mx = -__builtin_inff();
#pragma unroll
    for (int mi = 0; mi < 8; ++mi)
#pragma unroll
      for (int r = 0; r < 4; ++r) mx = fmaxf(mx, s[mi][r]);
    mx = fmaxf(mx, __shfl_xor(mx, 16));
    mx = fmaxf(mx, __shfl_xor(mx, 32));
    const float mn = fmaxf(mrun, mx * sscale);
    const float al = __builtin_amdgcn_exp2f(mrun - mn);
    mrun = mn;

    float rs = 0.f;
    s16x4 pb[8];
#pragma unroll
    for (int mi = 0; mi < 8; ++mi) {
      const float p0 = __builtin_amdgcn_exp2f(__builtin_fmaf(s[mi][0], sscale, -mn));
      const float p1 = __builtin_amdgcn_exp2f(__builtin_fmaf(s[mi][1], sscale, -mn));
      const float p2 = __builtin_amdgcn_exp2f(__builtin_fmaf(s[mi][2], sscale, -mn));
      const float p3 = __builtin_amdgcn_exp2f(__builtin_fmaf(s[mi][3], sscale, -mn));
      rs += (p0 + p1) + (p2 + p3);
      union { s16x4 v; unsigned u[2]; } pk;  // packed truncate f32->bf16 (1 op/pair)
      pk.u[0] = __builtin_amdgcn_perm(__float_as_uint(p1), __float_as_uint(p0), 0x07060302u);
      pk.u[1] = __builtin_amdgcn_perm(__float_as_uint(p3), __float_as_uint(p2), 0x07060302u);
      pb[mi] = pk.v;
    }
    rs += __shfl_xor(rs, 16);
    rs += __shfl_xor(rs, 32);
    lrun = lrun * al + rs;
#pragma unroll
    for (int dm = 0; dm < 4; ++dm) o[dm] *= al;

    // O^T += V^T * P^T
#pragma unroll
    for (int dm = 0; dm < 4; ++dm) {
      const unsigned short* vr = Vs + (dm * 16 + c) * 128 + (q & 1) * 4;
#pragma unroll
      for (int kf = 0; kf < 8; ++kf) {
        const s16x4 av = *reinterpret_cast<const s16x4*>(
            vr + (((kf * 2 + (q >> 1)) ^ cx) * 8));
        o[dm] = MFMA_PV(av, pb[kf], o[dm]);
      }
    }
  }

  const float linv = 1.0f / lrun;
  const int b = bh >> 4, h = bh & 15;
  const int row = b * SEQ + qsub * 64 + w * 16 + c;
#pragma unroll
  for (int dm = 0; dm < 4; ++dm) {
    ushort4 ov;
    ov.x = f2bf(o[dm][0] * linv);
    ov.y = f2bf(o[dm][1] * linv);
    ov.z = f2bf(o[dm][2] * linv);
    ov.w = f2bf(o[dm][3] * linv);
    *reinterpret_cast<ushort4*>(aout + (size_t)row * DMODEL + h * 64 + dm * 16 + q * 4) = ov;
  }
}

// ---------------- GEMM2: out = Aout[4096x1024] * WoutT[1024x1024]^T + b ----------------
__global__ __launch_bounds__(256) void k_gemm_out(
    const unsigned short* __restrict__ A, const unsigned short* __restrict__ Bt,
    const float* __restrict__ bias, float* __restrict__ C) {
  __shared__ __attribute__((aligned(16))) unsigned short As[128 * 32];
  __shared__ __attribute__((aligned(16))) unsigned short Bs[128 * 32];
  const int tid = threadIdx.x, lane = tid & 63;
  const int w = tid >> 6, wm = w >> 1, wn = w & 1;
  const int c = lane & 15, q = lane >> 4;
  const int bm = blockIdx.x * 128, bn = blockIdx.y * 128;
  const int srow = tid >> 2, scol = (tid & 3) * 8;
  const unsigned short* Ag = A + (size_t)(bm + srow) * DMODEL + scol;
  const unsigned short* Bg = Bt + (size_t)(bn + srow) * DMODEL + scol;
  f32x4 acc[4][4] = {};

  for (int kt = 0; kt < DMODEL / 32; ++kt) {
    if (kt) __syncthreads();
    const int k0 = kt * 32;
    gl_lds16(Ag + k0, As + tid * 8);
    gl_lds16(Ag + (size_t)64 * DMODEL + k0, As + 2048 + tid * 8);
    gl_lds16(Bg + k0, Bs + tid * 8);
    gl_lds16(Bg + (size_t)64 * DMODEL + k0, Bs + 2048 + tid * 8);
    __syncthreads();
    bf16x8 af[4], bfr[4];
#pragma unroll
    for (int i = 0; i < 4; ++i)
      af[i] = *reinterpret_cast<const bf16x8*>(As + (wm * 64 + i * 16 + c) * 32 + q * 8);
#pragma unroll
    for (int j = 0; j < 4; ++j)
      bfr[j] = *reinterpret_cast<const bf16x8*>(Bs + (wn * 64 + j * 16 + c) * 32 + q * 8);
#pragma unroll
    for (int i = 0; i < 4; ++i)
#pragma unroll
      for (int j = 0; j < 4; ++j)
        acc[i][j] = __builtin_amdgcn_mfma_f32_16x16x32_bf16(af[i], bfr[j], acc[i][j], 0, 0, 0);
  }

#pragma unroll
  for (int j = 0; j < 4; ++j) {
    const int gn = bn + wn * 64 + j * 16 + c;
    const float bv = bias[gn];
#pragma unroll
    for (int i = 0; i < 4; ++i)
#pragma unroll
      for (int r = 0; r < 4; ++r) {
        const int gm = bm + wm * 64 + i * 16 + q * 4 + r;
        C[(size_t)gm * DMODEL + gn] = acc[i][j][r] + bv;
      }
  }
}

extern "C" void kernel_launch(void* const* d_in, const int* in_sizes, int n_in,
                              void* d_out, int out_size, void* d_ws, size_t ws_size,
                              hipStream_t stream) {
  (void)in_sizes; (void)n_in; (void)out_size; (void)ws_size;
  const float* input = (const float*)d_in[0];
  // d_in[1] = causal mask, implemented analytically
  const float* W_qkv = (const float*)d_in[2];
  const float* b_qkv = (const float*)d_in[3];
  const float* W_out = (const float*)d_in[4];
  const float* b_out = (const float*)d_in[5];
  float* out = (float*)d_out;

  unsigned char* ws = (unsigned char*)d_ws;
  unsigned short* Abf   = (unsigned short*)(ws + 0);          // 8 MB; dead after GEMM1
  unsigned short* VTbf  = (unsigned short*)(ws + 0);          // aliases Abf [B,H,64,L]
  unsigned short* WqkvT = (unsigned short*)(ws + 8388608);    // 6 MB
  unsigned short* WoutT = (unsigned short*)(ws + 14680064);   // 2 MB
  unsigned short* Qbf   = (unsigned short*)(ws + 16777216);   // 8 MB [B,H,L,64]
  unsigned short* Kbf   = (unsigned short*)(ws + 25165824);   // 8 MB [B,H,L,64]
  unsigned short* Vbf   = (unsigned short*)(ws + 33554432);   // 8 MB [B,H,L,64]
  unsigned short* Aout  = (unsigned short*)(ws + 41943040);   // 8 MB [4096][1024]

  k_cvt_bf16<<<4096, 256, 0, stream>>>(input, Abf, 1048576);
  k_transpose_cvt<<<dim3(96, 32), dim3(32, 8), 0, stream>>>(W_qkv, WqkvT, 1024, 3072);
  k_transpose_cvt<<<dim3(32, 32), dim3(32, 8), 0, stream>>>(W_out, WoutT, 1024, 1024);
  k_gemm_qkv<<<dim3(32, 24), 256, 0, stream>>>(Abf, WqkvT, b_qkv, out, Qbf, Kbf, Vbf);
  k_vtrans<<<dim3(64, 2, 32), dim3(32, 8), 0, stream>>>(Vbf, VTbf);
  k_attn<<<1024, 256, 0, stream>>>(Qbf, Kbf, VTbf, Aout);
  k_gemm_out<<<dim3(32, 8), 256, 0, stream>>>(Aout, WoutT, b_out, out);
}

// Round 3
// 204.031 us; speedup vs baseline: 1.3140x; 1.1253x over previous
//
#include <hip/hip_runtime.h>
#include <cstdint>

#define NHEAD 16
#define DHEAD 64
#define SEQ   2048
#define DMODEL 1024
#define MTOT  4096
#define NQKV  3072

typedef __bf16 bf16x8 __attribute__((ext_vector_type(8)));
typedef short  s16x4  __attribute__((ext_vector_type(4)));
typedef float  f32x4  __attribute__((ext_vector_type(4)));

__device__ __forceinline__ unsigned short f2bf(float f) {
  union { float f; unsigned u; } v; v.f = f;
  unsigned r = v.u + 0x7fffu + ((v.u >> 16) & 1u);
  return (unsigned short)(r >> 16);
}

// async global->LDS, 16B per lane. LDS dest must be wave-uniform base + lane*16.
__device__ __forceinline__ void gl_lds16(const void* g, void* l) {
  __builtin_amdgcn_global_load_lds(
      reinterpret_cast<const __attribute__((address_space(1))) unsigned int*>(
          reinterpret_cast<uintptr_t>(g)),
      reinterpret_cast<__attribute__((address_space(3))) unsigned int*>(
          reinterpret_cast<uintptr_t>(l)),
      16, 0, 0);
}

#if __has_builtin(__builtin_amdgcn_mfma_f32_16x16x16bf16_1k)
#define MFMA_PV(a, b, c) __builtin_amdgcn_mfma_f32_16x16x16bf16_1k(a, b, c, 0, 0, 0)
#else
__device__ __forceinline__ f32x4 mfma_pv_asm(s16x4 a, s16x4 b, f32x4 c) {
  f32x4 d;
  asm volatile("v_mfma_f32_16x16x16_bf16 %0, %1, %2, %3"
               : "=v"(d) : "v"(a), "v"(b), "v"(c));
  return d;
}
#define MFMA_PV(a, b, c) mfma_pv_asm(a, b, c)
#endif

// ---------------- fp32 -> bf16 elementwise (input) ----------------
__global__ void k_cvt_bf16(const float* __restrict__ x,
                           unsigned short* __restrict__ y, int n4) {
  int i = blockIdx.x * blockDim.x + threadIdx.x;
  if (i >= n4) return;
  float4 v = reinterpret_cast<const float4*>(x)[i];
  ushort4 o;
  o.x = f2bf(v.x); o.y = f2bf(v.y); o.z = f2bf(v.z); o.w = f2bf(v.w);
  reinterpret_cast<ushort4*>(y)[i] = o;
}

// ---------------- both weight transposes in one launch ----------------
// W[K=1024][N] fp32 -> WT[N][1024] bf16;  x<96 -> W_qkv(N=3072), else W_out(N=1024)
__global__ void k_transpose_cvt2(const float* __restrict__ W0, unsigned short* __restrict__ T0,
                                 const float* __restrict__ W1, unsigned short* __restrict__ T1) {
  __shared__ unsigned short t[32][33];
  const int bx = blockIdx.x;
  const float* W = (bx < 96) ? W0 : W1;
  unsigned short* WT = (bx < 96) ? T0 : T1;
  const int N = (bx < 96) ? 3072 : 1024;
  const int n0 = ((bx < 96) ? bx : (bx - 96)) * 32;
  const int k0 = blockIdx.y * 32;
  const int tx = threadIdx.x, ty = threadIdx.y;
  for (int i = ty; i < 32; i += 8)
    t[i][tx] = f2bf(W[(size_t)(k0 + i) * N + n0 + tx]);
  __syncthreads();
  for (int i = ty; i < 32; i += 8)
    WT[(size_t)(n0 + i) * 1024 + k0 + tx] = t[tx][i];
}

// ---------------- bf16 V [bh][tok][64] -> V^T [bh][64][tok] ----------------
__global__ void k_vtrans(const unsigned short* __restrict__ v,
                         unsigned short* __restrict__ vt) {
  __shared__ unsigned short t[32][33];
  const int bh = blockIdx.z;
  const int t0 = blockIdx.x * 32, d0 = blockIdx.y * 32;
  const int tx = threadIdx.x, ty = threadIdx.y;
  const unsigned short* vb = v + (size_t)bh * SEQ * DHEAD;
  unsigned short* vtb = vt + (size_t)bh * DHEAD * SEQ;
  for (int i = ty; i < 32; i += 8)
    t[i][tx] = vb[(size_t)(t0 + i) * DHEAD + d0 + tx];
  __syncthreads();
  for (int i = ty; i < 32; i += 8)
    vtb[(size_t)(d0 + i) * SEQ + t0 + tx] = t[tx][i];
}

// ---------------- GEMM1: qkv = A[4096x1024] * WqkvT[3072x1024]^T + b ----------------
// BK=64, XOR-swizzled LDS staging (conflict-free b128 frag reads)
__global__ __launch_bounds__(256, 3) void k_gemm_qkv(
    const unsigned short* __restrict__ A, const unsigned short* __restrict__ Bt,
    const float* __restrict__ bias, float* __restrict__ outbase,
    unsigned short* __restrict__ qbf, unsigned short* __restrict__ kbf,
    unsigned short* __restrict__ vbf) {
  __shared__ __attribute__((aligned(16))) unsigned short As[128 * 64];
  __shared__ __attribute__((aligned(16))) unsigned short Bs[128 * 64];
  const int tid = threadIdx.x, lane = tid & 63;
  const int w = tid >> 6, wm = w >> 1, wn = w & 1;
  const int c = lane & 15, q = lane >> 4, cx = c & 7;
  const int bm = blockIdx.x * 128, bn = blockIdx.y * 128;
  const int srow = tid >> 3, swz8 = ((tid & 7) ^ (srow & 7)) * 8;
  const unsigned short* Ag = A + (size_t)(bm + srow) * DMODEL + swz8;
  const unsigned short* Bg = Bt + (size_t)(bn + srow) * DMODEL + swz8;
  f32x4 acc[4][4] = {};

  for (int kt = 0; kt < DMODEL / 64; ++kt) {
    if (kt) __syncthreads();
    const int k0 = kt * 64;
#pragma unroll
    for (int is = 0; is < 4; ++is) {
      gl_lds16(Ag + k0 + is * 32 * DMODEL, As + is * 2048 + tid * 8);
      gl_lds16(Bg + k0 + is * 32 * DMODEL, Bs + is * 2048 + tid * 8);
    }
    __syncthreads();
#pragma unroll
    for (int k32 = 0; k32 < 2; ++k32) {
      const int ch = ((k32 << 2) | q) ^ cx;
      bf16x8 af[4], bfr[4];
#pragma unroll
      for (int i = 0; i < 4; ++i)
        af[i] = *reinterpret_cast<const bf16x8*>(As + (wm * 64 + i * 16 + c) * 64 + ch * 8);
#pragma unroll
      for (int j = 0; j < 4; ++j)
        bfr[j] = *reinterpret_cast<const bf16x8*>(Bs + (wn * 64 + j * 16 + c) * 64 + ch * 8);
#pragma unroll
      for (int i = 0; i < 4; ++i)
#pragma unroll
        for (int j = 0; j < 4; ++j)
          acc[i][j] = __builtin_amdgcn_mfma_f32_16x16x32_bf16(af[i], bfr[j], acc[i][j], 0, 0, 0);
    }
  }

  const int sec = bn >> 10;  // 0=q 1=k 2=v (block-uniform)
#pragma unroll
  for (int j = 0; j < 4; ++j) {
    const int gn = bn + wn * 64 + j * 16 + c;
    const float bv = bias[gn];
    const int cc = gn & 1023, hh = cc >> 6, dd = cc & 63;
#pragma unroll
    for (int i = 0; i < 4; ++i) {
#pragma unroll
      for (int r = 0; r < 4; ++r) {
        const int gm = bm + wm * 64 + i * 16 + q * 4 + r;
        const int bb = gm >> 11, tok = gm & 2047;
        const float val = acc[i][j][r] + bv;
        const size_t hoff = ((size_t)(bb * NHEAD + hh) * SEQ + tok) * DHEAD + dd;
        if (sec == 0) {
          qbf[hoff] = f2bf(val);
        } else if (sec == 1) {
          outbase[(size_t)4194304 + (size_t)gm * DMODEL + cc] = val;
          kbf[hoff] = f2bf(val);
        } else {
          outbase[(size_t)8388608 + (size_t)gm * DMODEL + cc] = val;
          vbf[hoff] = f2bf(val);
        }
      }
    }
  }
}

// ---------------- flash attention (causal), S^T trick, 64-row Q tiles ----------------
__global__ __launch_bounds__(256) void k_attn(
    const unsigned short* __restrict__ qbf, const unsigned short* __restrict__ kbf,
    const unsigned short* __restrict__ vtbf, unsigned short* __restrict__ aout) {
  __shared__ __attribute__((aligned(16))) unsigned short Ks[128 * 64];
  __shared__ __attribute__((aligned(16))) unsigned short Vs[64 * 128];

  const int tid = threadIdx.x, lane = tid & 63, w = tid >> 6;
  const int c = lane & 15, q = lane >> 4;
  const int oo = blockIdx.x >> 5, kk = oo & 7, ssl = oo >> 3;
  const int qsub = (ssl == 0) ? (31 - kk) : (ssl == 1) ? kk
                 : (ssl == 2) ? (23 - kk) : (8 + kk);
  const int bh = blockIdx.x & 31;
  const int kmax = qsub >> 1;
  const size_t hoff = (size_t)bh * SEQ * DHEAD;

  const unsigned short* qg = qbf + hoff + (size_t)(qsub * 64 + w * 16 + c) * DHEAD;
  const bf16x8 qb0 = *reinterpret_cast<const bf16x8*>(qg + q * 8);
  const bf16x8 qb1 = *reinterpret_cast<const bf16x8*>(qg + 32 + q * 8);

  f32x4 o[4] = {};
  float mrun = -__builtin_inff(), lrun = 0.f;
  const float sscale = 0.125f * 1.44269504088896340736f;
  const int qloc = (qsub & 1) * 64 + w * 16 + c;
  const int cx = c & 7;

  const int krow = tid >> 3, kswz = (tid & 7) ^ (krow & 7);
  const int vrow = tid >> 4, vswz = (tid & 15) ^ (vrow & 7);
  const unsigned short* kgb = kbf + hoff;
  const unsigned short* vgb = vtbf + (size_t)bh * DHEAD * SEQ;

  for (int kt = 0; kt <= kmax; ++kt) {
    __syncthreads();
    const unsigned short* kg = kgb + (size_t)kt * 128 * DHEAD;
#pragma unroll
    for (int is = 0; is < 4; ++is)
      gl_lds16(kg + (krow + is * 32) * 64 + kswz * 8, Ks + is * 2048 + tid * 8);
    const unsigned short* vg = vgb + kt * 128;
#pragma unroll
    for (int is = 0; is < 4; ++is)
      gl_lds16(vg + (size_t)(vrow + is * 16) * SEQ + vswz * 8, Vs + is * 2048 + tid * 8);
    __syncthreads();

    f32x4 s[8];
#pragma unroll
    for (int mi = 0; mi < 8; ++mi) {
      const unsigned short* kr = Ks + (mi * 16 + c) * 64;
      const bf16x8 ak0 = *reinterpret_cast<const bf16x8*>(kr + (q ^ cx) * 8);
      const bf16x8 ak1 = *reinterpret_cast<const bf16x8*>(kr + ((4 + q) ^ cx) * 8);
      f32x4 t = {};
      t = __builtin_amdgcn_mfma_f32_16x16x32_bf16(ak0, qb0, t, 0, 0, 0);
      t = __builtin_amdgcn_mfma_f32_16x16x32_bf16(ak1, qb1, t, 0, 0, 0);
      s[mi] = t;
    }

    if (kt == kmax) {
#pragma unroll
      for (int mi = 0; mi < 8; ++mi)
#pragma unroll
        for (int r = 0; r < 4; ++r)
          if (mi * 16 + q * 4 + r > qloc) s[mi][r] = -__builtin_inff();
    }

    float mx = -__builtin_inff();
#pragma unroll
    for (int mi = 0; mi < 8; ++mi)
#pragma unroll
      for (int r = 0; r < 4; ++r) mx = fmaxf(mx, s[mi][r]);
    mx = fmaxf(mx, __shfl_xor(mx, 16));
    mx = fmaxf(mx, __shfl_xor(mx, 32));
    const float mn = fmaxf(mrun, mx * sscale);
    const float al = __builtin_amdgcn_exp2f(mrun - mn);
    mrun = mn;

    float rs = 0.f;
    s16x4 pb[8];
#pragma unroll
    for (int mi = 0; mi < 8; ++mi) {
      const float p0 = __builtin_amdgcn_exp2f(__builtin_fmaf(s[mi][0], sscale, -mn));
      const float p1 = __builtin_amdgcn_exp2f(__builtin_fmaf(s[mi][1], sscale, -mn));
      const float p2 = __builtin_amdgcn_exp2f(__builtin_fmaf(s[mi][2], sscale, -mn));
      const float p3 = __builtin_amdgcn_exp2f(__builtin_fmaf(s[mi][3], sscale, -mn));
      rs += (p0 + p1) + (p2 + p3);
      union { s16x4 v; unsigned u[2]; } pk;
      pk.u[0] = __builtin_amdgcn_perm(__float_as_uint(p1), __float_as_uint(p0), 0x07060302u);
      pk.u[1] = __builtin_amdgcn_perm(__float_as_uint(p3), __float_as_uint(p2), 0x07060302u);
      pb[mi] = pk.v;
    }
    rs += __shfl_xor(rs, 16);
    rs += __shfl_xor(rs, 32);
    lrun = lrun * al + rs;
#pragma unroll
    for (int dm = 0; dm < 4; ++dm) o[dm] *= al;

#pragma unroll
    for (int dm = 0; dm < 4; ++dm) {
      const unsigned short* vr = Vs + (dm * 16 + c) * 128 + (q & 1) * 4;
#pragma unroll
      for (int kf = 0; kf < 8; ++kf) {
        const s16x4 av = *reinterpret_cast<const s16x4*>(
            vr + (((kf * 2 + (q >> 1)) ^ cx) * 8));
        o[dm] = MFMA_PV(av, pb[kf], o[dm]);
      }
    }
  }

  const float linv = 1.0f / lrun;
  const int b = bh >> 4, h = bh & 15;
  const int row = b * SEQ + qsub * 64 + w * 16 + c;
#pragma unroll
  for (int dm = 0; dm < 4; ++dm) {
    ushort4 ov;
    ov.x = f2bf(o[dm][0] * linv);
    ov.y = f2bf(o[dm][1] * linv);
    ov.z = f2bf(o[dm][2] * linv);
    ov.w = f2bf(o[dm][3] * linv);
    *reinterpret_cast<ushort4*>(aout + (size_t)row * DMODEL + h * 64 + dm * 16 + q * 4) = ov;
  }
}

// ---------------- GEMM2: out = Aout[4096x1024] * WoutT[1024x1024]^T + b ----------------
// 128x64 tiles (512 blocks = 2/CU), BK=64, XOR-swizzled staging
__global__ __launch_bounds__(256) void k_gemm_out(
    const unsigned short* __restrict__ A, const unsigned short* __restrict__ Bt,
    const float* __restrict__ bias, float* __restrict__ C) {
  __shared__ __attribute__((aligned(16))) unsigned short As[128 * 64];
  __shared__ __attribute__((aligned(16))) unsigned short Bs[64 * 64];
  const int tid = threadIdx.x, lane = tid & 63;
  const int w = tid >> 6, wm = w >> 1, wn = w & 1;
  const int c = lane & 15, q = lane >> 4, cx = c & 7;
  const int bm = blockIdx.x * 128, bn = blockIdx.y * 64;
  const int srow = tid >> 3, swz8 = ((tid & 7) ^ (srow & 7)) * 8;
  const unsigned short* Ag = A + (size_t)(bm + srow) * DMODEL + swz8;
  const unsigned short* Bg = Bt + (size_t)(bn + srow) * DMODEL + swz8;
  f32x4 acc[4][2] = {};

  for (int kt = 0; kt < DMODEL / 64; ++kt) {
    if (kt) __syncthreads();
    const int k0 = kt * 64;
#pragma unroll
    for (int is = 0; is < 4; ++is)
      gl_lds16(Ag + k0 + is * 32 * DMODEL, As + is * 2048 + tid * 8);
#pragma unroll
    for (int is = 0; is < 2; ++is)
      gl_lds16(Bg + k0 + is * 32 * DMODEL, Bs + is * 2048 + tid * 8);
    __syncthreads();
#pragma unroll
    for (int k32 = 0; k32 < 2; ++k32) {
      const int ch = ((k32 << 2) | q) ^ cx;
      bf16x8 af[4], bfr[2];
#pragma unroll
      for (int i = 0; i < 4; ++i)
        af[i] = *reinterpret_cast<const bf16x8*>(As + (wm * 64 + i * 16 + c) * 64 + ch * 8);
#pragma unroll
      for (int j = 0; j < 2; ++j)
        bfr[j] = *reinterpret_cast<const bf16x8*>(Bs + (wn * 32 + j * 16 + c) * 64 + ch * 8);
#pragma unroll
      for (int i = 0; i < 4; ++i)
#pragma unroll
        for (int j = 0; j < 2; ++j)
          acc[i][j] = __builtin_amdgcn_mfma_f32_16x16x32_bf16(af[i], bfr[j], acc[i][j], 0, 0, 0);
    }
  }

#pragma unroll
  for (int j = 0; j < 2; ++j) {
    const int gn = bn + wn * 32 + j * 16 + c;
    const float bv = bias[gn];
#pragma unroll
    for (int i = 0; i < 4; ++i)
#pragma unroll
      for (int r = 0; r < 4; ++r) {
        const int gm = bm + wm * 64 + i * 16 + q * 4 + r;
        C[(size_t)gm * DMODEL + gn] = acc[i][j][r] + bv;
      }
  }
}

extern "C" void kernel_launch(void* const* d_in, const int* in_sizes, int n_in,
                              void* d_out, int out_size, void* d_ws, size_t ws_size,
                              hipStream_t stream) {
  (void)in_sizes; (void)n_in; (void)out_size; (void)ws_size;
  const float* input = (const float*)d_in[0];
  // d_in[1] = causal mask, implemented analytically
  const float* W_qkv = (const float*)d_in[2];
  const float* b_qkv = (const float*)d_in[3];
  const float* W_out = (const float*)d_in[4];
  const float* b_out = (const float*)d_in[5];
  float* out = (float*)d_out;

  unsigned char* ws = (unsigned char*)d_ws;
  unsigned short* Abf   = (unsigned short*)(ws + 0);          // 8 MB; dead after GEMM1
  unsigned short* VTbf  = (unsigned short*)(ws + 0);          // aliases Abf [B,H,64,L]
  unsigned short* WqkvT = (unsigned short*)(ws + 8388608);    // 6 MB
  unsigned short* WoutT = (unsigned short*)(ws + 14680064);   // 2 MB
  unsigned short* Qbf   = (unsigned short*)(ws + 16777216);   // 8 MB [B,H,L,64]
  unsigned short* Kbf   = (unsigned short*)(ws + 25165824);   // 8 MB [B,H,L,64]
  unsigned short* Vbf   = (unsigned short*)(ws + 33554432);   // 8 MB [B,H,L,64]
  unsigned short* Aout  = (unsigned short*)(ws + 41943040);   // 8 MB [4096][1024]

  k_cvt_bf16<<<4096, 256, 0, stream>>>(input, Abf, 1048576);
  k_transpose_cvt2<<<dim3(128, 32), dim3(32, 8), 0, stream>>>(W_qkv, WqkvT, W_out, WoutT);
  k_gemm_qkv<<<dim3(32, 24), 256, 0, stream>>>(Abf, WqkvT, b_qkv, out, Qbf, Kbf, Vbf);
  k_vtrans<<<dim3(64, 2, 32), dim3(32, 8), 0, stream>>>(Vbf, VTbf);
  k_attn<<<1024, 256, 0, stream>>>(Qbf, Kbf, VTbf, Aout);
  k_gemm_out<<<dim3(32, 16), 256, 0, stream>>>(Aout, WoutT, b_out, out);
}

// Round 5
// 201.673 us; speedup vs baseline: 1.3294x; 1.0117x over previous
//
#include <hip/hip_runtime.h>
#include <cstdint>

#define NHEAD 16
#define DHEAD 64
#define SEQ   2048
#define DMODEL 1024
#define MTOT  4096
#define NQKV  3072

typedef __bf16 bf16x8 __attribute__((ext_vector_type(8)));
typedef short  s16x4  __attribute__((ext_vector_type(4)));
typedef float  f32x4  __attribute__((ext_vector_type(4)));

__device__ __forceinline__ unsigned short f2bf(float f) {
  union { float f; unsigned u; } v; v.f = f;
  unsigned r = v.u + 0x7fffu + ((v.u >> 16) & 1u);
  return (unsigned short)(r >> 16);
}

// async global->LDS, 16B per lane. LDS dest must be wave-uniform base + lane*16.
__device__ __forceinline__ void gl_lds16(const void* g, void* l) {
  __builtin_amdgcn_global_load_lds(
      reinterpret_cast<const __attribute__((address_space(1))) unsigned int*>(
          reinterpret_cast<uintptr_t>(g)),
      reinterpret_cast<__attribute__((address_space(3))) unsigned int*>(
          reinterpret_cast<uintptr_t>(l)),
      16, 0, 0);
}

#if __has_builtin(__builtin_amdgcn_mfma_f32_16x16x16bf16_1k)
#define MFMA_PV(a, b, c) __builtin_amdgcn_mfma_f32_16x16x16bf16_1k(a, b, c, 0, 0, 0)
#else
__device__ __forceinline__ f32x4 mfma_pv_asm(s16x4 a, s16x4 b, f32x4 c) {
  f32x4 d;
  asm volatile("v_mfma_f32_16x16x16_bf16 %0, %1, %2, %3"
               : "=v"(d) : "v"(a), "v"(b), "v"(c));
  return d;
}
#define MFMA_PV(a, b, c) mfma_pv_asm(a, b, c)
#endif

// ---------------- fp32 -> bf16 elementwise (input) ----------------
__global__ void k_cvt_bf16(const float* __restrict__ x,
                           unsigned short* __restrict__ y, int n4) {
  int i = blockIdx.x * blockDim.x + threadIdx.x;
  if (i >= n4) return;
  float4 v = reinterpret_cast<const float4*>(x)[i];
  ushort4 o;
  o.x = f2bf(v.x); o.y = f2bf(v.y); o.z = f2bf(v.z); o.w = f2bf(v.w);
  reinterpret_cast<ushort4*>(y)[i] = o;
}

// ---------------- both weight transposes in one launch ----------------
__global__ void k_transpose_cvt2(const float* __restrict__ W0, unsigned short* __restrict__ T0,
                                 const float* __restrict__ W1, unsigned short* __restrict__ T1) {
  __shared__ unsigned short t[32][33];
  const int bx = blockIdx.x;
  const float* W = (bx < 96) ? W0 : W1;
  unsigned short* WT = (bx < 96) ? T0 : T1;
  const int N = (bx < 96) ? 3072 : 1024;
  const int n0 = ((bx < 96) ? bx : (bx - 96)) * 32;
  const int k0 = blockIdx.y * 32;
  const int tx = threadIdx.x, ty = threadIdx.y;
  for (int i = ty; i < 32; i += 8)
    t[i][tx] = f2bf(W[(size_t)(k0 + i) * N + n0 + tx]);
  __syncthreads();
  for (int i = ty; i < 32; i += 8)
    WT[(size_t)(n0 + i) * 1024 + k0 + tx] = t[tx][i];
}

// ---------------- bf16 V [bh][tok][64] -> V^T [bh][64][tok] ----------------
__global__ void k_vtrans(const unsigned short* __restrict__ v,
                         unsigned short* __restrict__ vt) {
  __shared__ unsigned short t[32][33];
  const int bh = blockIdx.z;
  const int t0 = blockIdx.x * 32, d0 = blockIdx.y * 32;
  const int tx = threadIdx.x, ty = threadIdx.y;
  const unsigned short* vb = v + (size_t)bh * SEQ * DHEAD;
  unsigned short* vtb = vt + (size_t)bh * DHEAD * SEQ;
  for (int i = ty; i < 32; i += 8)
    t[i][tx] = vb[(size_t)(t0 + i) * DHEAD + d0 + tx];
  __syncthreads();
  for (int i = ty; i < 32; i += 8)
    vtb[(size_t)(d0 + i) * SEQ + t0 + tx] = t[tx][i];
}

// ---------------- GEMM1: double-buffered LDS, 1 barrier/iter, BK=32 ----------------
// gl_lds16 with SOURCE-side XOR swizzle: LDS[row][x] = G[row][x ^ skey(row)];
// frag reads at chunk q^kc are the measured-conflict-free R3 pattern.
__global__ __launch_bounds__(256, 3) void k_gemm_qkv(
    const unsigned short* __restrict__ A, const unsigned short* __restrict__ Bt,
    const float* __restrict__ bias, float* __restrict__ outbase,
    unsigned short* __restrict__ qbf, unsigned short* __restrict__ kbf,
    unsigned short* __restrict__ vbf) {
  __shared__ __attribute__((aligned(16))) unsigned short As[2][128 * 32];
  __shared__ __attribute__((aligned(16))) unsigned short Bs[2][128 * 32];
  const int tid = threadIdx.x, lane = tid & 63;
  const int w = tid >> 6, wm = w >> 1, wn = w & 1;
  const int c = lane & 15, q = lane >> 4;
  const int kc = (c & 3) ^ ((c >> 2) & 3);        // frag-read swizzle key
  const int bm = blockIdx.x * 128, bn = blockIdx.y * 128;
  const int srow = tid >> 2;
  const int skey = (srow & 3) ^ ((srow >> 2) & 3);
  const int scolsw = (((tid & 3) ^ skey) << 3);   // swizzled global source column
  const unsigned short* Ag = A + (size_t)(bm + srow) * DMODEL + scolsw;
  const unsigned short* Bg = Bt + (size_t)(bn + srow) * DMODEL + scolsw;
  f32x4 acc[4][4] = {};

  // stage tile 0 into buf 0
  gl_lds16(Ag, As[0] + tid * 8);
  gl_lds16(Ag + (size_t)64 * DMODEL, As[0] + 2048 + tid * 8);
  gl_lds16(Bg, Bs[0] + tid * 8);
  gl_lds16(Bg + (size_t)64 * DMODEL, Bs[0] + 2048 + tid * 8);

  for (int kt = 0; kt < 32; ++kt) {
    const int cur = kt & 1;
    __syncthreads();  // drains loads issued LAST iter (fully latency-hidden)
    if (kt < 31) {    // prefetch tile kt+1 into the other buffer
      const int k0 = (kt + 1) * 32;
      gl_lds16(Ag + k0, As[cur ^ 1] + tid * 8);
      gl_lds16(Ag + k0 + (size_t)64 * DMODEL, As[cur ^ 1] + 2048 + tid * 8);
      gl_lds16(Bg + k0, Bs[cur ^ 1] + tid * 8);
      gl_lds16(Bg + k0 + (size_t)64 * DMODEL, Bs[cur ^ 1] + 2048 + tid * 8);
    }
    const int ch = (q ^ kc) << 3;
    bf16x8 af[4], bfr[4];
#pragma unroll
    for (int i = 0; i < 4; ++i)
      af[i] = *reinterpret_cast<const bf16x8*>(As[cur] + (wm * 64 + i * 16 + c) * 32 + ch);
#pragma unroll
    for (int j = 0; j < 4; ++j)
      bfr[j] = *reinterpret_cast<const bf16x8*>(Bs[cur] + (wn * 64 + j * 16 + c) * 32 + ch);
#pragma unroll
    for (int i = 0; i < 4; ++i)
#pragma unroll
      for (int j = 0; j < 4; ++j)
        acc[i][j] = __builtin_amdgcn_mfma_f32_16x16x32_bf16(af[i], bfr[j], acc[i][j], 0, 0, 0);
  }

  const int sec = bn >> 10;  // 0=q 1=k 2=v (block-uniform)
#pragma unroll
  for (int j = 0; j < 4; ++j) {
    const int gn = bn + wn * 64 + j * 16 + c;
    const float bv = bias[gn];
    const int cc = gn & 1023, hh = cc >> 6, dd = cc & 63;
#pragma unroll
    for (int i = 0; i < 4; ++i) {
#pragma unroll
      for (int r = 0; r < 4; ++r) {
        const int gm = bm + wm * 64 + i * 16 + q * 4 + r;
        const int bb = gm >> 11, tok = gm & 2047;
        const float val = acc[i][j][r] + bv;
        const size_t hoff = ((size_t)(bb * NHEAD + hh) * SEQ + tok) * DHEAD + dd;
        if (sec == 0) {
          qbf[hoff] = f2bf(val);
        } else if (sec == 1) {
          outbase[(size_t)4194304 + (size_t)gm * DMODEL + cc] = val;
          kbf[hoff] = f2bf(val);
        } else {
          outbase[(size_t)8388608 + (size_t)gm * DMODEL + cc] = val;
          vbf[hoff] = f2bf(val);
        }
      }
    }
  }
}

// ---------------- flash attention (causal), S^T trick, 64-row Q tiles ----------------
// (R3-verified version, unchanged)
__global__ __launch_bounds__(256) void k_attn(
    const unsigned short* __restrict__ qbf, const unsigned short* __restrict__ kbf,
    const unsigned short* __restrict__ vtbf, unsigned short* __restrict__ aout) {
  __shared__ __attribute__((aligned(16))) unsigned short Ks[128 * 64];
  __shared__ __attribute__((aligned(16))) unsigned short Vs[64 * 128];

  const int tid = threadIdx.x, lane = tid & 63, w = tid >> 6;
  const int c = lane & 15, q = lane >> 4;
  const int oo = blockIdx.x >> 5, kk = oo & 7, ssl = oo >> 3;
  const int qsub = (ssl == 0) ? (31 - kk) : (ssl == 1) ? kk
                 : (ssl == 2) ? (23 - kk) : (8 + kk);
  const int bh = blockIdx.x & 31;
  const int kmax = qsub >> 1;
  const size_t hoff = (size_t)bh * SEQ * DHEAD;

  const unsigned short* qg = qbf + hoff + (size_t)(qsub * 64 + w * 16 + c) * DHEAD;
  const bf16x8 qb0 = *reinterpret_cast<const bf16x8*>(qg + q * 8);
  const bf16x8 qb1 = *reinterpret_cast<const bf16x8*>(qg + 32 + q * 8);

  f32x4 o[4] = {};
  float mrun = -__builtin_inff(), lrun = 0.f;
  const float sscale = 0.125f * 1.44269504088896340736f;
  const int qloc = (qsub & 1) * 64 + w * 16 + c;
  const int cx = c & 7;

  const int krow = tid >> 3, kswz = (tid & 7) ^ (krow & 7);
  const int vrow = tid >> 4, vswz = (tid & 15) ^ (vrow & 7);
  const unsigned short* kgb = kbf + hoff;
  const unsigned short* vgb = vtbf + (size_t)bh * DHEAD * SEQ;

  for (int kt = 0; kt <= kmax; ++kt) {
    __syncthreads();
    const unsigned short* kg = kgb + (size_t)kt * 128 * DHEAD;
#pragma unroll
    for (int is = 0; is < 4; ++is)
      gl_lds16(kg + (krow + is * 32) * 64 + kswz * 8, Ks + is * 2048 + tid * 8);
    const unsigned short* vg = vgb + kt * 128;
#pragma unroll
    for (int is = 0; is < 4; ++is)
      gl_lds16(vg + (size_t)(vrow + is * 16) * SEQ + vswz * 8, Vs + is * 2048 + tid * 8);
    __syncthreads();

    f32x4 s[8];
#pragma unroll
    for (int mi = 0; mi < 8; ++mi) {
      const unsigned short* kr = Ks + (mi * 16 + c) * 64;
      const bf16x8 ak0 = *reinterpret_cast<const bf16x8*>(kr + (q ^ cx) * 8);
      const bf16x8 ak1 = *reinterpret_cast<const bf16x8*>(kr + ((4 + q) ^ cx) * 8);
      f32x4 t = {};
      t = __builtin_amdgcn_mfma_f32_16x16x32_bf16(ak0, qb0, t, 0, 0, 0);
      t = __builtin_amdgcn_mfma_f32_16x16x32_bf16(ak1, qb1, t, 0, 0, 0);
      s[mi] = t;
    }

    if (kt == kmax) {
#pragma unroll
      for (int mi = 0; mi < 8; ++mi)
#pragma unroll
        for (int r = 0; r < 4; ++r)
          if (mi * 16 + q * 4 + r > qloc) s[mi][r] = -__builtin_inff();
    }

    float mx = -__builtin_inff();
#pragma unroll
    for (int mi = 0; mi < 8; ++mi)
#pragma unroll
      for (int r = 0; r < 4; ++r) mx = fmaxf(mx, s[mi][r]);
    mx = fmaxf(mx, __shfl_xor(mx, 16));
    mx = fmaxf(mx, __shfl_xor(mx, 32));
    const float mn = fmaxf(mrun, mx * sscale);
    const float al = __builtin_amdgcn_exp2f(mrun - mn);
    mrun = mn;

    float rs = 0.f;
    s16x4 pb[8];
#pragma unroll
    for (int mi = 0; mi < 8; ++mi) {
      const float p0 = __builtin_amdgcn_exp2f(__builtin_fmaf(s[mi][0], sscale, -mn));
      const float p1 = __builtin_amdgcn_exp2f(__builtin_fmaf(s[mi][1], sscale, -mn));
      const float p2 = __builtin_amdgcn_exp2f(__builtin_fmaf(s[mi][2], sscale, -mn));
      const float p3 = __builtin_amdgcn_exp2f(__builtin_fmaf(s[mi][3], sscale, -mn));
      rs += (p0 + p1) + (p2 + p3);
      union { s16x4 v; unsigned u[2]; } pk;
      pk.u[0] = __builtin_amdgcn_perm(__float_as_uint(p1), __float_as_uint(p0), 0x07060302u);
      pk.u[1] = __builtin_amdgcn_perm(__float_as_uint(p3), __float_as_uint(p2), 0x07060302u);
      pb[mi] = pk.v;
    }
    rs += __shfl_xor(rs, 16);
    rs += __shfl_xor(rs, 32);
    lrun = lrun * al + rs;
#pragma unroll
    for (int dm = 0; dm < 4; ++dm) o[dm] *= al;

#pragma unroll
    for (int dm = 0; dm < 4; ++dm) {
      const unsigned short* vr = Vs + (dm * 16 + c) * 128 + (q & 1) * 4;
#pragma unroll
      for (int kf = 0; kf < 8; ++kf) {
        const s16x4 av = *reinterpret_cast<const s16x4*>(
            vr + (((kf * 2 + (q >> 1)) ^ cx) * 8));
        o[dm] = MFMA_PV(av, pb[kf], o[dm]);
      }
    }
  }

  const float linv = 1.0f / lrun;
  const int b = bh >> 4, h = bh & 15;
  const int row = b * SEQ + qsub * 64 + w * 16 + c;
#pragma unroll
  for (int dm = 0; dm < 4; ++dm) {
    ushort4 ov;
    ov.x = f2bf(o[dm][0] * linv);
    ov.y = f2bf(o[dm][1] * linv);
    ov.z = f2bf(o[dm][2] * linv);
    ov.w = f2bf(o[dm][3] * linv);
    *reinterpret_cast<ushort4*>(aout + (size_t)row * DMODEL + h * 64 + dm * 16 + q * 4) = ov;
  }
}

// ---------------- GEMM2: 128x64 tiles, double-buffered, BK=32 ----------------
__global__ __launch_bounds__(256) void k_gemm_out(
    const unsigned short* __restrict__ A, const unsigned short* __restrict__ Bt,
    const float* __restrict__ bias, float* __restrict__ C) {
  __shared__ __attribute__((aligned(16))) unsigned short As[2][128 * 32];
  __shared__ __attribute__((aligned(16))) unsigned short Bs[2][64 * 32];
  const int tid = threadIdx.x, lane = tid & 63;
  const int w = tid >> 6, wm = w >> 1, wn = w & 1;
  const int c = lane & 15, q = lane >> 4;
  const int kc = (c & 3) ^ ((c >> 2) & 3);
  const int bm = blockIdx.x * 128, bn = blockIdx.y * 64;
  const int srow = tid >> 2;
  const int skey = (srow & 3) ^ ((srow >> 2) & 3);
  const int scolsw = (((tid & 3) ^ skey) << 3);
  const unsigned short* Ag = A + (size_t)(bm + srow) * DMODEL + scolsw;
  const unsigned short* Bg = Bt + (size_t)(bn + srow) * DMODEL + scolsw;
  f32x4 acc[4][2] = {};

  gl_lds16(Ag, As[0] + tid * 8);
  gl_lds16(Ag + (size_t)64 * DMODEL, As[0] + 2048 + tid * 8);
  gl_lds16(Bg, Bs[0] + tid * 8);

  for (int kt = 0; kt < 32; ++kt) {
    const int cur = kt & 1;
    __syncthreads();
    if (kt < 31) {
      const int k0 = (kt + 1) * 32;
      gl_lds16(Ag + k0, As[cur ^ 1] + tid * 8);
      gl_lds16(Ag + k0 + (size_t)64 * DMODEL, As[cur ^ 1] + 2048 + tid * 8);
      gl_lds16(Bg + k0, Bs[cur ^ 1] + tid * 8);
    }
    const int ch = (q ^ kc) << 3;
    bf16x8 af[4], bfr[2];
#pragma unroll
    for (int i = 0; i < 4; ++i)
      af[i] = *reinterpret_cast<const bf16x8*>(As[cur] + (wm * 64 + i * 16 + c) * 32 + ch);
#pragma unroll
    for (int j = 0; j < 2; ++j)
      bfr[j] = *reinterpret_cast<const bf16x8*>(Bs[cur] + (wn * 32 + j * 16 + c) * 32 + ch);
#pragma unroll
    for (int i = 0; i < 4; ++i)
#pragma unroll
      for (int j = 0; j < 2; ++j)
        acc[i][j] = __builtin_amdgcn_mfma_f32_16x16x32_bf16(af[i], bfr[j], acc[i][j], 0, 0, 0);
  }

#pragma unroll
  for (int j = 0; j < 2; ++j) {
    const int gn = bn + wn * 32 + j * 16 + c;
    const float bv = bias[gn];
#pragma unroll
    for (int i = 0; i < 4; ++i)
#pragma unroll
      for (int r = 0; r < 4; ++r) {
        const int gm = bm + wm * 64 + i * 16 + q * 4 + r;
        C[(size_t)gm * DMODEL + gn] = acc[i][j][r] + bv;
      }
  }
}

extern "C" void kernel_launch(void* const* d_in, const int* in_sizes, int n_in,
                              void* d_out, int out_size, void* d_ws, size_t ws_size,
                              hipStream_t stream) {
  (void)in_sizes; (void)n_in; (void)out_size; (void)ws_size;
  const float* input = (const float*)d_in[0];
  // d_in[1] = causal mask, implemented analytically
  const float* W_qkv = (const float*)d_in[2];
  const float* b_qkv = (const float*)d_in[3];
  const float* W_out = (const float*)d_in[4];
  const float* b_out = (const float*)d_in[5];
  float* out = (float*)d_out;

  unsigned char* ws = (unsigned char*)d_ws;
  unsigned short* Abf   = (unsigned short*)(ws + 0);          // 8 MB; dead after GEMM1
  unsigned short* VTbf  = (unsigned short*)(ws + 0);          // aliases Abf [B,H,64,L]
  unsigned short* WqkvT = (unsigned short*)(ws + 8388608);    // 6 MB
  unsigned short* WoutT = (unsigned short*)(ws + 14680064);   // 2 MB
  unsigned short* Qbf   = (unsigned short*)(ws + 16777216);   // 8 MB [B,H,L,64]
  unsigned short* Kbf   = (unsigned short*)(ws + 25165824);   // 8 MB [B,H,L,64]
  unsigned short* Vbf   = (unsigned short*)(ws + 33554432);   // 8 MB [B,H,L,64]
  unsigned short* Aout  = (unsigned short*)(ws + 41943040);   // 8 MB [4096][1024]

  k_cvt_bf16<<<4096, 256, 0, stream>>>(input, Abf, 1048576);
  k_transpose_cvt2<<<dim3(128, 32), dim3(32, 8), 0, stream>>>(W_qkv, WqkvT, W_out, WoutT);
  k_gemm_qkv<<<dim3(32, 24), 256, 0, stream>>>(Abf, WqkvT, b_qkv, out, Qbf, Kbf, Vbf);
  k_vtrans<<<dim3(64, 2, 32), dim3(32, 8), 0, stream>>>(Vbf, VTbf);
  k_attn<<<1024, 256, 0, stream>>>(Qbf, Kbf, VTbf, Aout);
  k_gemm_out<<<dim3(32, 16), 256, 0, stream>>>(Aout, WoutT, b_out, out);
}